// Round 7
// baseline (476.794 us; speedup 1.0000x reference)
//
#include <hip/hip_runtime.h>

#define BB 4
#define CC 96
#define LL 32
#define HH 56
#define WW 56
#define HW (HH * WW)
#define KD 16
#define CH 14   // chunk/tile size: live set = acc[14]+xch[14] -> never spills

// ---- bf16 pack/unpack helpers (x stored in LDS as packed bf16 pairs) ----
__device__ __forceinline__ unsigned rne16(float f) {           // RNE, result in top 16 bits
    unsigned u = __float_as_uint(f);
    return u + 0x7fffu + ((u >> 16) & 1u);
}
__device__ __forceinline__ unsigned packbf(float a, float b) {
    return (rne16(a) >> 16) | (rne16(b) & 0xffff0000u);
}
__device__ __forceinline__ float lo16(unsigned u) { return __uint_as_float(u << 16); }
__device__ __forceinline__ float hi16(unsigned u) { return __uint_as_float(u & 0xffff0000u); }

// ---------------------------------------------------------------------------
// Pass 1: fused causal conv along W then H, per (b,c,l) 56x56 slice.
// 4 waves/block, each wave owns one slice. Slice lives in LDS as bf16 pairs
// (26 KB/block -> 6 blocks/CU, 24 waves/CU). Tiled in-place triangular conv,
// output tiles DESCENDING (tile t only overwrites input chunk t). Taps are
// wave-uniform global reads -> SGPR operands of v_fma.
// ---------------------------------------------------------------------------
__global__ __launch_bounds__(256, 6) void conv_wh(const float* __restrict__ x,
                                                  const float* __restrict__ wconv,
                                                  const float* __restrict__ hconv,
                                                  float* __restrict__ out) {
    __shared__ unsigned slu[4][HH][29];   // 28 data dwords + 1 pad (odd stride)

    const int tid  = threadIdx.x;
    const int wv   = tid >> 6;
    const int lane = tid & 63;
    const int slice0 = blockIdx.x * 4;
    const int c      = (slice0 / LL) % CC;
    const float* __restrict__ kw = wconv + c * WW;   // uniform -> scalar loads
    const float* __restrict__ kh = hconv + c * HH;

    // cooperative load: 1568 float2 per slice, pack to bf16 pairs
    const size_t base = (size_t)(slice0 + wv) * HW;
    const float2* xs = (const float2*)(x + base);
    #pragma unroll
    for (int i = 0; i < 25; ++i) {
        int d = i * 64 + lane;
        if (d < HW / 2) {
            float2 v = xs[d];
            slu[wv][d / 28][d % 28] = packbf(v.x, v.y);
        }
    }
    __syncthreads();

    // ---- W pass: lane = row h; in-place on the row, tiles descending ----
    if (lane < HH) {
        unsigned* rowp = &slu[wv][lane][0];
        #pragma unroll
        for (int t = 3; t >= 0; --t) {
            const int w0 = t * CH;
            float acc[CH];
            #pragma unroll
            for (int i = 0; i < CH; ++i) acc[i] = 0.f;
            // off-diagonal input chunks u < t (full 27-diagonal band)
            #pragma unroll
            for (int u = 0; u < t; ++u) {
                const int u0 = u * CH;
                float xch[CH];
                #pragma unroll
                for (int jj = 0; jj < CH / 2; ++jj) {
                    unsigned v = rowp[7 * u + jj];
                    xch[2 * jj]     = lo16(v);
                    xch[2 * jj + 1] = hi16(v);
                }
                #pragma unroll
                for (int dd = 0; dd < 2 * CH - 1; ++dd) {
                    const float kd = kw[w0 - u0 - (CH - 1) + dd];
                    const int delta = dd - (CH - 1);
                    #pragma unroll
                    for (int j = 0; j < CH; ++j) {
                        const int i = j + delta;
                        if (i >= 0 && i < CH)
                            acc[i] = fmaf(kd, xch[j], acc[i]);
                    }
                }
            }
            // diagonal chunk (u == t): triangular
            {
                float xch[CH];
                #pragma unroll
                for (int jj = 0; jj < CH / 2; ++jj) {
                    unsigned v = rowp[7 * t + jj];
                    xch[2 * jj]     = lo16(v);
                    xch[2 * jj + 1] = hi16(v);
                }
                #pragma unroll
                for (int dd = 0; dd < CH; ++dd) {
                    const float kd = kw[dd];
                    #pragma unroll
                    for (int j = 0; j < CH - dd; ++j)
                        acc[j + dd] = fmaf(kd, xch[j], acc[j + dd]);
                }
            }
            #pragma unroll
            for (int jj = 0; jj < CH / 2; ++jj)
                rowp[7 * t + jj] = packbf(acc[2 * jj], acc[2 * jj + 1]);
        }
    }
    __syncthreads();

    // ---- H pass: lane = column w; reads columns, writes global fp32 ----
    if (lane < WW) {
        const int wq  = lane >> 1;
        const bool od = lane & 1;
        #pragma unroll
        for (int t = 3; t >= 0; --t) {
            const int h0 = t * CH;
            float acc[CH];
            #pragma unroll
            for (int i = 0; i < CH; ++i) acc[i] = 0.f;
            #pragma unroll
            for (int u = 0; u < t; ++u) {
                const int u0 = u * CH;
                float xch[CH];
                #pragma unroll
                for (int j = 0; j < CH; ++j) {
                    unsigned v = slu[wv][u0 + j][wq];
                    xch[j] = od ? hi16(v) : lo16(v);
                }
                #pragma unroll
                for (int dd = 0; dd < 2 * CH - 1; ++dd) {
                    const float kd = kh[h0 - u0 - (CH - 1) + dd];
                    const int delta = dd - (CH - 1);
                    #pragma unroll
                    for (int j = 0; j < CH; ++j) {
                        const int i = j + delta;
                        if (i >= 0 && i < CH)
                            acc[i] = fmaf(kd, xch[j], acc[i]);
                    }
                }
            }
            {
                float xch[CH];
                #pragma unroll
                for (int j = 0; j < CH; ++j) {
                    unsigned v = slu[wv][h0 + j][wq];
                    xch[j] = od ? hi16(v) : lo16(v);
                }
                #pragma unroll
                for (int dd = 0; dd < CH; ++dd) {
                    const float kd = kh[dd];
                    #pragma unroll
                    for (int j = 0; j < CH - dd; ++j)
                        acc[j + dd] = fmaf(kd, xch[j], acc[j + dd]);
                }
            }
            #pragma unroll
            for (int i = 0; i < CH; ++i)
                out[base + (size_t)(h0 + i) * WW + lane] = acc[i];
        }
    }
}

// ---------------------------------------------------------------------------
// Pass 2: causal conv along L, in-place on out. One thread per TWO (b,c,h,w)
// positions (float2); reads all 32 l before writing -> in-place race-free.
// No launch_bounds cap: xin2[32]+kr[32] ~ 110 VGPR, must not spill.
// ---------------------------------------------------------------------------
__global__ void conv_l(float* __restrict__ y,
                       const float* __restrict__ k0,
                       const float* __restrict__ k1,
                       const float* __restrict__ decay) {
    __shared__ float kl[LL];
    __shared__ float s_norm;

    const int tid = threadIdx.x;
    const int bc  = blockIdx.y;             // b*C + c
    const int c   = bc % CC;

    if (tid < LL) {
        float v;
        const float dec = decay[c];
        if (tid < KD) {
            v = k0[c * KD + tid] * dec;     // kernel0 * decay^1
        } else {
            // linear interp (scale=2, align_corners=False) of kernel1, first 16
            const int   i    = tid - KD;
            const float src  = fmaxf((i + 0.5f) * 0.5f - 0.5f, 0.f);
            const int   lo   = (int)floorf(src);
            const float frac = src - (float)lo;
            const int   hi   = min(lo + 1, KD - 1);
            v = k1[c * KD + lo] * (1.f - frac) + k1[c * KD + hi] * frac;
        }
        kl[tid] = v;
    }
    __syncthreads();
    if (tid == 0) {
        float s = 0.f;
        for (int i = 0; i < LL; ++i) s += kl[i] * kl[i];
        s_norm = sqrtf(s);
    }
    __syncthreads();

    const float inv = 1.0f / s_norm;
    float kr[LL];
    #pragma unroll
    for (int i = 0; i < LL; ++i) kr[i] = kl[i] * inv;

    const int pos2 = blockIdx.x * 256 + tid;        // float2 index within HW
    if (pos2 >= HW / 2) return;

    float2* col = (float2*)(y + (size_t)bc * LL * HW) + pos2;
    float2 xin[LL];
    #pragma unroll
    for (int l = 0; l < LL; ++l) xin[l] = col[(size_t)l * (HW / 2)];

    // in-place causal conv, descending l: xin[j<l] still original when used
    #pragma unroll
    for (int l = LL - 1; l >= 0; --l) {
        float tx = 0.f, ty = 0.f;
        #pragma unroll
        for (int j = 0; j <= l; ++j) {
            tx = fmaf(kr[l - j], xin[j].x, tx);
            ty = fmaf(kr[l - j], xin[j].y, ty);
        }
        xin[l].x = tx; xin[l].y = ty;
    }
    #pragma unroll
    for (int l = 0; l < LL; ++l) col[(size_t)l * (HW / 2)] = xin[l];
}

// ---------------------------------------------------------------------------
extern "C" void kernel_launch(void* const* d_in, const int* in_sizes, int n_in,
                              void* d_out, int out_size, void* d_ws, size_t ws_size,
                              hipStream_t stream) {
    const float* x     = (const float*)d_in[0];
    const float* wconv = (const float*)d_in[1];
    const float* hconv = (const float*)d_in[2];
    const float* k0    = (const float*)d_in[3];
    const float* k1    = (const float*)d_in[4];
    const float* dec   = (const float*)d_in[5];
    float*       out   = (float*)d_out;

    conv_wh<<<dim3(BB * CC * LL / 4), 256, 0, stream>>>(x, wconv, hconv, out);
    conv_l<<<dim3((HW / 2 + 255) / 256, BB * CC), 256, 0, stream>>>(out, k0, k1, dec);
}